// Round 1
// baseline (186.641 us; speedup 1.0000x reference)
//
#include <hip/hip_runtime.h>
#include <math.h>

// Problem constants (from reference): V videos, D embedding dim, K=2F+1 basis.
#define V 128
#define D 64
#define K 13

#define CHUNK 4096        // elements per sort block
#define SORT_BLOCK 256
#define NB 256            // sorted n's per compute block
#define BSTRIDE 20        // floats per basis row in LDS (16B-aligned, 8-way-max write conflicts)

// ---------------- Kernel 1: per-block histogram (no global atomics) ----------------
__global__ __launch_bounds__(256) void hist_kernel(const int* __restrict__ ids, int n,
                                                   int* __restrict__ blockhist) {
    __shared__ int h[V];
    int tid = threadIdx.x;
    if (tid < V) h[tid] = 0;
    __syncthreads();
    int base = blockIdx.x * CHUNK;
#pragma unroll
    for (int j = 0; j < CHUNK / SORT_BLOCK; ++j) {
        int i = base + j * SORT_BLOCK + tid;
        if (i < n) atomicAdd(&h[ids[i]], 1);
    }
    __syncthreads();
    if (tid < V) blockhist[blockIdx.x * V + tid] = h[tid];
}

// ---------------- Kernel 2: scan -> per-(block,bin) base offsets ----------------
__global__ __launch_bounds__(V) void scan_kernel(const int* __restrict__ blockhist,
                                                 int* __restrict__ blockbase,
                                                 int nblk) {
    __shared__ int binbase[V];
    int t = threadIdx.x;  // one thread per bin
    int cum = 0;
    for (int b = 0; b < nblk; ++b) {
        blockbase[b * V + t] = cum;          // exclusive prefix within bin
        cum += blockhist[b * V + t];
    }
    __shared__ int totals[V];
    totals[t] = cum;
    __syncthreads();
    if (t == 0) {
        int s = 0;
        for (int v = 0; v < V; ++v) { binbase[v] = s; s += totals[v]; }
    }
    __syncthreads();
    int bb = binbase[t];
    for (int b = 0; b < nblk; ++b) blockbase[b * V + t] += bb;
}

// ---------------- Kernel 3: rank + scatter (LDS atomics only, deterministic set) ----------------
__global__ __launch_bounds__(256) void scatter_kernel(const int* __restrict__ ids, int n,
                                                      const int* __restrict__ blockbase,
                                                      int* __restrict__ sorted_idx) {
    __shared__ int h[V];
    __shared__ int lb[V];
    int tid = threadIdx.x;
    if (tid < V) {
        h[tid] = 0;
        lb[tid] = blockbase[blockIdx.x * V + tid];
    }
    __syncthreads();
    int base = blockIdx.x * CHUNK;
#pragma unroll
    for (int j = 0; j < CHUNK / SORT_BLOCK; ++j) {
        int i = base + j * SORT_BLOCK + tid;
        if (i < n) {
            int v = ids[i];
            int r = atomicAdd(&h[v], 1);     // rank within (block, bin); any order is a valid bijection
            sorted_idx[lb[v] + r] = i;
        }
    }
}

// ---------------- Kernel 4: compute. Wave = 64 lanes = 64 d's; weights register-cached per lane ----------------
__global__ __launch_bounds__(256) void compute_kernel(const float* __restrict__ times,
                                                      const int* __restrict__ ids,
                                                      const float* __restrict__ weights,
                                                      const int* __restrict__ sorted_idx,
                                                      float* __restrict__ out, int n) {
    __shared__ float basis[NB * BSTRIDE];
    __shared__ int svid[NB];
    __shared__ int sidx[NB];
    int tid = threadIdx.x;
    int g = blockIdx.x * NB + tid;

    // Phase 1: one thread per n — gather t, vid; build 13-entry Fourier basis in LDS.
    if (g < n) {
        int idx = sorted_idx[g];             // coalesced
        float t = times[idx];                // L2-hit gather (times = 1.6 MB, fits per-XCD L2)
        int v = ids[idx];
        sidx[tid] = idx;
        svid[tid] = v;
        float s, c;
        __sincosf(3.14159265358979323846f * t, &s, &c);
        float sj[6], cj[6];
        sj[0] = s; cj[0] = c;
#pragma unroll
        for (int j = 1; j < 6; ++j) {        // double-angle: sin/cos(2^j * pi * t)
            sj[j] = 2.0f * sj[j - 1] * cj[j - 1];
            cj[j] = 1.0f - 2.0f * sj[j - 1] * sj[j - 1];
        }
        float4* bp = (float4*)&basis[tid * BSTRIDE];
        bp[0] = make_float4(1.0f, sj[0], sj[1], sj[2]);
        bp[1] = make_float4(sj[3], sj[4], sj[5], cj[0]);
        bp[2] = make_float4(cj[1], cj[2], cj[3], cj[4]);
        bp[3] = make_float4(cj[5], 0.0f, 0.0f, 0.0f);
    }
    __syncthreads();

    // Phase 2: each wave sweeps 64 sorted n's; lane = d. Weights live in 13 VGPRs,
    // reloaded only on (wave-uniform) vid change — sorted order makes that rare.
    int wave = tid >> 6;
    int lane = tid & 63;
    int i0 = wave * 64;
    int rem = n - blockIdx.x * NB - i0;
    int iend = rem < 64 ? (rem < 0 ? 0 : rem) : 64;

    int cur = -1;
    float w[K];
    for (int i = 0; i < iend; ++i) {
        int ii = i0 + i;
        int v = svid[ii];                    // LDS broadcast
        if (v != cur) {                      // wave-uniform branch
            cur = v;
            const float* wp = weights + ((long)v * D + lane) * K;
#pragma unroll
            for (int k = 0; k < K; ++k) w[k] = wp[k];
        }
        const float4* bp = (const float4*)&basis[ii * BSTRIDE];
        float4 b0 = bp[0], b1 = bp[1], b2 = bp[2];
        float b12 = basis[ii * BSTRIDE + 12];
        float acc = b0.x * w[0] + b0.y * w[1] + b0.z * w[2] + b0.w * w[3]
                  + b1.x * w[4] + b1.y * w[5] + b1.z * w[6] + b1.w * w[7]
                  + b2.x * w[8] + b2.y * w[9] + b2.z * w[10] + b2.w * w[11]
                  + b12 * w[12];
        out[(long)sidx[ii] * D + lane] = acc;  // 256B contiguous per wave
    }
}

extern "C" void kernel_launch(void* const* d_in, const int* in_sizes, int n_in,
                              void* d_out, int out_size, void* d_ws, size_t ws_size,
                              hipStream_t stream) {
    const float* times = (const float*)d_in[0];
    const int* ids = (const int*)d_in[1];
    const float* weights = (const float*)d_in[2];
    float* out = (float*)d_out;
    int n = in_sizes[0];

    int nblk = (n + CHUNK - 1) / CHUNK;
    // Workspace layout (all fully overwritten every call; no reliance on zeroing):
    //   blockhist: nblk*V ints | blockbase: nblk*V ints | sorted_idx: n ints  (~1.7 MB total)
    int* blockhist = (int*)d_ws;
    int* blockbase = blockhist + (size_t)nblk * V;
    int* sorted_idx = blockbase + (size_t)nblk * V;

    hist_kernel<<<nblk, SORT_BLOCK, 0, stream>>>(ids, n, blockhist);
    scan_kernel<<<1, V, 0, stream>>>(blockhist, blockbase, nblk);
    scatter_kernel<<<nblk, SORT_BLOCK, 0, stream>>>(ids, n, blockbase, sorted_idx);

    int nblk4 = (n + NB - 1) / NB;
    compute_kernel<<<nblk4, 256, 0, stream>>>(times, ids, weights, sorted_idx, out, n);
}

// Round 2
// 143.484 us; speedup vs baseline: 1.3008x; 1.3008x over previous
//
#include <hip/hip_runtime.h>
#include <math.h>

// Problem constants (from reference): V videos, D embedding dim, K=2F+1 basis.
#define V 128
#define D 64
#define K 13

#define CHUNK 4096        // elements per sort block
#define SORT_BLOCK 256
#define NB 256            // sorted n's per compute block
#define BSTRIDE 20        // floats per basis row in LDS (16B-aligned)

// ---------------- Kernel 1: per-block histogram (no global atomics, int4 loads) ----------------
__global__ __launch_bounds__(256) void hist_kernel(const int* __restrict__ ids, int n,
                                                   int* __restrict__ blockhist) {
    __shared__ int h[V];
    int tid = threadIdx.x;
    if (tid < V) h[tid] = 0;
    __syncthreads();
    int base = blockIdx.x * CHUNK;
#pragma unroll
    for (int j = 0; j < CHUNK / (SORT_BLOCK * 4); ++j) {
        int i = base + (j * SORT_BLOCK + tid) * 4;    // 16B aligned; n % 4 == 0
        if (i < n) {
            int4 v4 = *(const int4*)(ids + i);
            atomicAdd(&h[v4.x], 1);
            atomicAdd(&h[v4.y], 1);
            atomicAdd(&h[v4.z], 1);
            atomicAdd(&h[v4.w], 1);
        }
    }
    __syncthreads();
    if (tid < V) blockhist[blockIdx.x * V + tid] = h[tid];
}

// ---------------- Kernel 2: scan, fully in LDS (one block, coalesced I/O) ----------------
__global__ __launch_bounds__(256) void scan_kernel(const int* __restrict__ blockhist,
                                                   int* __restrict__ blockbase,
                                                   int nblk) {
    extern __shared__ int lh[];                        // nblk * V ints (~50 KB)
    __shared__ int totals[V];
    __shared__ int sc[V];
    int tid = threadIdx.x;
    int total = nblk * V;
    for (int idx = tid; idx < total; idx += 256) lh[idx] = blockhist[idx];  // parallel coalesced
    __syncthreads();
    if (tid < V) {                                     // per-bin exclusive prefix, conflict-free LDS
        int cum = 0;
        for (int b = 0; b < nblk; ++b) {
            int x = lh[b * V + tid];
            lh[b * V + tid] = cum;
            cum += x;
        }
        totals[tid] = cum;
        sc[tid] = cum;
    }
    __syncthreads();
    for (int off = 1; off < V; off <<= 1) {            // Hillis-Steele inclusive scan of totals
        int v = 0;
        if (tid < V && tid >= off) v = sc[tid - off];
        __syncthreads();
        if (tid < V) sc[tid] += v;
        __syncthreads();
    }
    if (tid < V) totals[tid] = sc[tid] - totals[tid];  // exclusive bin base
    __syncthreads();
    for (int idx = tid; idx < total; idx += 256)       // parallel coalesced writeback
        blockbase[idx] = lh[idx] + totals[idx & (V - 1)];
}

// ---------------- Kernel 3: rank + scatter (LDS atomics only, int4 loads) ----------------
__global__ __launch_bounds__(256) void scatter_kernel(const int* __restrict__ ids, int n,
                                                      const int* __restrict__ blockbase,
                                                      int* __restrict__ sorted_idx) {
    __shared__ int h[V];
    __shared__ int lb[V];
    int tid = threadIdx.x;
    if (tid < V) {
        h[tid] = 0;
        lb[tid] = blockbase[blockIdx.x * V + tid];
    }
    __syncthreads();
    int base = blockIdx.x * CHUNK;
#pragma unroll
    for (int j = 0; j < CHUNK / (SORT_BLOCK * 4); ++j) {
        int i = base + (j * SORT_BLOCK + tid) * 4;
        if (i < n) {
            int4 v4 = *(const int4*)(ids + i);
            int r0 = atomicAdd(&h[v4.x], 1); sorted_idx[lb[v4.x] + r0] = i;
            int r1 = atomicAdd(&h[v4.y], 1); sorted_idx[lb[v4.y] + r1] = i + 1;
            int r2 = atomicAdd(&h[v4.z], 1); sorted_idx[lb[v4.z] + r2] = i + 2;
            int r3 = atomicAdd(&h[v4.w], 1); sorted_idx[lb[v4.w] + r3] = i + 3;
        }
    }
}

// ---------------- Kernel 4: compute. Wave = 64 lanes = 64 d's; weights register-cached ----------------
__global__ __launch_bounds__(256) void compute_kernel(const float* __restrict__ times,
                                                      const int* __restrict__ ids,
                                                      const float* __restrict__ weights,
                                                      const int* __restrict__ sorted_idx,
                                                      float* __restrict__ out, int n) {
    __shared__ float basis[NB * BSTRIDE];
    __shared__ int svid[NB];
    __shared__ int sidx[NB];
    int tid = threadIdx.x;
    int g = blockIdx.x * NB + tid;

    // Phase 1: one thread per n — gather t, vid; build 13-entry Fourier basis in LDS.
    if (g < n) {
        int idx = sorted_idx[g];             // coalesced
        float t = times[idx];                // L2-hit gather (times = 1.6 MB)
        int v = ids[idx];
        sidx[tid] = idx;
        svid[tid] = v;
        float s, c;
        __sincosf(3.14159265358979323846f * t, &s, &c);
        float sj[6], cj[6];
        sj[0] = s; cj[0] = c;
#pragma unroll
        for (int j = 1; j < 6; ++j) {        // double-angle: sin/cos(2^j * pi * t)
            sj[j] = 2.0f * sj[j - 1] * cj[j - 1];
            cj[j] = 1.0f - 2.0f * sj[j - 1] * sj[j - 1];
        }
        float4* bp = (float4*)&basis[tid * BSTRIDE];
        bp[0] = make_float4(1.0f, sj[0], sj[1], sj[2]);
        bp[1] = make_float4(sj[3], sj[4], sj[5], cj[0]);
        bp[2] = make_float4(cj[1], cj[2], cj[3], cj[4]);
        bp[3] = make_float4(cj[5], 0.0f, 0.0f, 0.0f);
    }
    __syncthreads();

    // Phase 2: each wave sweeps 64 sorted n's; lane = d. svid/sidx held in regs,
    // broadcast via __shfl (2 VALU ops replace 2 long-latency LDS reads per iter).
    int wave = tid >> 6;
    int lane = tid & 63;
    int i0 = wave * 64;
    int rem = n - blockIdx.x * NB - i0;
    int iend = rem < 64 ? (rem < 0 ? 0 : rem) : 64;

    int vreg = 0, ireg = 0;
    if (blockIdx.x * NB + i0 + lane < n) {
        vreg = svid[i0 + lane];
        ireg = sidx[i0 + lane];
    }

    int cur = -1;
    float w[K];
    for (int i = 0; i < iend; ++i) {
        int v = __shfl(vreg, i, 64);         // wave-uniform broadcast from lane i
        int idx = __shfl(ireg, i, 64);
        if (v != cur) {                      // wave-uniform branch; rare after sort
            cur = v;
            const float* wp = weights + ((long)v * D + lane) * K;
#pragma unroll
            for (int k = 0; k < K; ++k) w[k] = wp[k];
        }
        int ii = i0 + i;
        const float4* bp = (const float4*)&basis[ii * BSTRIDE];
        float4 b0 = bp[0], b1 = bp[1], b2 = bp[2];
        float b12 = basis[ii * BSTRIDE + 12];
        // balanced tree: dependent-chain depth ~4 instead of 12
        float acc = ((b0.x * w[0] + b0.y * w[1]) + (b0.z * w[2] + b0.w * w[3]))
                  + ((b1.x * w[4] + b1.y * w[5]) + (b1.z * w[6] + b1.w * w[7]))
                  + (((b2.x * w[8] + b2.y * w[9]) + (b2.z * w[10] + b2.w * w[11]))
                     + b12 * w[12]);
        out[(long)idx * D + lane] = acc;     // 256B contiguous per wave
    }
}

extern "C" void kernel_launch(void* const* d_in, const int* in_sizes, int n_in,
                              void* d_out, int out_size, void* d_ws, size_t ws_size,
                              hipStream_t stream) {
    const float* times = (const float*)d_in[0];
    const int* ids = (const int*)d_in[1];
    const float* weights = (const float*)d_in[2];
    float* out = (float*)d_out;
    int n = in_sizes[0];

    int nblk = (n + CHUNK - 1) / CHUNK;
    // Workspace layout (all fully overwritten every call):
    //   blockhist: nblk*V ints | blockbase: nblk*V ints | sorted_idx: n ints  (~1.7 MB)
    int* blockhist = (int*)d_ws;
    int* blockbase = blockhist + (size_t)nblk * V;
    int* sorted_idx = blockbase + (size_t)nblk * V;

    hist_kernel<<<nblk, SORT_BLOCK, 0, stream>>>(ids, n, blockhist);
    scan_kernel<<<1, 256, (size_t)nblk * V * sizeof(int), stream>>>(blockhist, blockbase, nblk);
    scatter_kernel<<<nblk, SORT_BLOCK, 0, stream>>>(ids, n, blockbase, sorted_idx);

    int nblk4 = (n + NB - 1) / NB;
    compute_kernel<<<nblk4, 256, 0, stream>>>(times, ids, weights, sorted_idx, out, n);
}